// Round 16
// baseline (485.446 us; speedup 1.0000x reference)
//
#include <hip/hip_runtime.h>
#include <hip/hip_bf16.h>

#define NN 100000
#define NE 1600000
#define IN_DIM 33
#define HID 128
#define NG 128
#define NCLS 10

using short8 = __attribute__((ext_vector_type(8))) short;
using floatx4 = __attribute__((ext_vector_type(4))) float;

static __device__ __forceinline__ size_t szmul(int a, int b) {
    return (size_t)a * (size_t)b;
}

// bf16 helpers: pack with RNE, unpack via bit ops (cheap: 1 VALU each)
static __device__ __forceinline__ unsigned short f2bf(float f) {
    unsigned u = __float_as_uint(f);
    u += 0x7fffu + ((u >> 16) & 1u);
    return (unsigned short)(u >> 16);
}
static __device__ __forceinline__ float bf_lo(unsigned u) { return __uint_as_float(u << 16); }
static __device__ __forceinline__ float bf_hi(unsigned u) { return __uint_as_float(u & 0xffff0000u); }

// ---------------- init ----------------
__global__ void k_init(int* bucket_cnt, int* bucket_fill, float* gsum) {
    int i = blockIdx.x * blockDim.x + threadIdx.x;
    if (i < 513) { bucket_cnt[i] = 0; bucket_fill[i] = 0; }
    if (i < NG * HID) gsum[i] = 0.0f;
}

// ---------------- binned CSR build ----------------
// bucket = col >> 8 (256 nodes per bucket, nbk = ceil(N/256) = 391)

__global__ __launch_bounds__(256) void k_bhist(const int* __restrict__ col,
                                               int* __restrict__ bucket_cnt, int e, int nbk) {
    __shared__ int hist[512];
    int tid = threadIdx.x;
    for (int i = tid; i < nbk; i += 256) hist[i] = 0;
    __syncthreads();
    for (int i = blockIdx.x * 256 + tid; i < e; i += 256 * 256)
        atomicAdd(&hist[col[i] >> 8], 1);
    __syncthreads();
    for (int i = tid; i < nbk; i += 256)
        if (hist[i]) atomicAdd(&bucket_cnt[i], hist[i]);
}

// parallel exclusive scan over nb <= 512 elements, in place; data[nb] = total
__global__ void k_scan_small(int* data, int nb) {
    __shared__ int s[512];
    int t = threadIdx.x;
    int v = (t < nb) ? data[t] : 0;
    s[t] = v;
    __syncthreads();
    for (int o = 1; o < 512; o <<= 1) {
        int a = (t >= o) ? s[t - o] : 0;
        __syncthreads();
        s[t] += a;
        __syncthreads();
    }
    if (t < nb) data[t] = s[t] - v;
    if (t == nb - 1) data[nb] = s[t];
}

// Pass C: binned scatter. 4096 edges/block, vectorized int4/float4 input reads;
// multisplit by bucket in LDS, grouped writes per bucket.
// Record: x = (col&255)<<17 | src (src < 2^17), y = raw w bits.
__global__ __launch_bounds__(256) void k_bin_scatter(const int* __restrict__ row,
                                                     const int* __restrict__ col,
                                                     const float* __restrict__ w,
                                                     const int* __restrict__ bucket_base,
                                                     int* __restrict__ bucket_fill,
                                                     uint2* __restrict__ binned, int e, int nbk) {
    __shared__ int hist[512], rnk[512], basub[512];
    int tid = threadIdx.x;
    int c0 = blockIdx.x * 4096;
    for (int i = tid; i < nbk; i += 256) { hist[i] = 0; rnk[i] = 0; }
    __syncthreads();
    int base = c0 + tid * 16;
    int myb[16]; unsigned myp[16]; unsigned myw[16];
    if (base + 16 <= e) {
#pragma unroll
        for (int q = 0; q < 4; ++q) {
            int4 c4 = reinterpret_cast<const int4*>(col + base)[q];
            int4 r4 = reinterpret_cast<const int4*>(row + base)[q];
            float4 w4 = reinterpret_cast<const float4*>(w + base)[q];
            int cs[4] = {c4.x, c4.y, c4.z, c4.w};
            int rs[4] = {r4.x, r4.y, r4.z, r4.w};
            float ws[4] = {w4.x, w4.y, w4.z, w4.w};
#pragma unroll
            for (int v = 0; v < 4; ++v) {
                int c = cs[v];
                int b = c >> 8;
                myb[q * 4 + v] = b;
                myp[q * 4 + v] = ((unsigned)(c & 255) << 17) | (unsigned)rs[v];
                myw[q * 4 + v] = __float_as_uint(ws[v]);
                atomicAdd(&hist[b], 1);
            }
        }
    } else {
#pragma unroll
        for (int v = 0; v < 16; ++v) {
            int idx = base + v;
            int b = -1;
            if (idx < e) {
                int c = col[idx];
                myw[v] = __float_as_uint(w[idx]);
                b = c >> 8;
                myp[v] = ((unsigned)(c & 255) << 17) | (unsigned)row[idx];
                atomicAdd(&hist[b], 1);
            }
            myb[v] = b;
        }
    }
    __syncthreads();
    for (int i = tid; i < nbk; i += 256) {
        int c = hist[i];
        basub[i] = (c > 0) ? (bucket_base[i] + atomicAdd(&bucket_fill[i], c)) : 0;
    }
    __syncthreads();
#pragma unroll
    for (int u = 0; u < 16; ++u) {
        int b = myb[u];
        if (b >= 0) {
            int rk = atomicAdd(&rnk[b], 1);
            binned[basub[b] + rk] = make_uint2(myp[u], myw[u]);
        }
    }
}

// Pass D1: per-bucket node histogram + weight sums; in-LDS scan -> rowptr directly
__global__ __launch_bounds__(256) void k_bucket_rowptr(const uint2* __restrict__ binned,
                                                       const int* __restrict__ bucket_base,
                                                       int* __restrict__ rowptr,
                                                       float* __restrict__ wsum, int n) {
    __shared__ int c256[256];
    __shared__ float s256[256];
    __shared__ int sc[256];
    int b = blockIdx.x, tid = threadIdx.x;
    c256[tid] = 0;
    s256[tid] = 0.0f;
    __syncthreads();
    int beg = bucket_base[b], end = bucket_base[b + 1];
    for (int e2 = beg + tid; e2 < end; e2 += 256) {
        uint2 rec = binned[e2];
        int lo = (rec.x >> 17) & 255;
        atomicAdd(&c256[lo], 1);
        atomicAdd(&s256[lo], __uint_as_float(rec.y));
    }
    __syncthreads();
    int v = c256[tid];
    sc[tid] = v;
    __syncthreads();
    for (int o = 1; o < 256; o <<= 1) {
        int a = (tid >= o) ? sc[tid - o] : 0;
        __syncthreads();
        sc[tid] += a;
        __syncthreads();
    }
    int node = b * 256 + tid;
    if (node < n) {
        rowptr[node] = beg + sc[tid] - v;   // exclusive prefix within bucket
        wsum[node] = s256[tid];
    }
}

// dinv/selfn from wsum (in place on dinv buffer); also sets rowptr[N] = E
__global__ void k_dinv(float* __restrict__ dinv, float* __restrict__ selfn,
                       int* __restrict__ rowptr, int n, int etot) {
    int i = blockIdx.x * blockDim.x + threadIdx.x;
    if (i == n) rowptr[n] = etot;
    if (i >= n) return;
    float d = 1.0f + dinv[i];
    float di = (d > 0.0f) ? (1.0f / sqrtf(d)) : 0.0f;
    dinv[i] = di;
    selfn[i] = di * di;
}

// Pass D2: per-bucket final scatter with normalization folded in
__global__ __launch_bounds__(256) void k_bucket_scatter(const uint2* __restrict__ binned,
                                                        const int* __restrict__ bucket_base,
                                                        const int* __restrict__ rowptr,
                                                        const float* __restrict__ dinv,
                                                        int2* __restrict__ csr, int n) {
    __shared__ int f256[256];
    int b = blockIdx.x, tid = threadIdx.x;
    f256[tid] = 0;
    __syncthreads();
    int beg = bucket_base[b], end = bucket_base[b + 1];
    for (int e2 = beg + tid; e2 < end; e2 += 256) {
        uint2 rec = binned[e2];
        int lo = (rec.x >> 17) & 255;
        int node = (b << 8) | lo;
        int src = rec.x & 0x1FFFF;
        float nw = dinv[src] * __uint_as_float(rec.y) * dinv[node];
        int pos = rowptr[node] + atomicAdd(&f256[lo], 1);
        csr[pos] = make_int2(src, __float_as_int(nw));
    }
    (void)n;
}

// ---------------- fused weights: M = We@W1 [33x128], v = be@W1 [128] ----------------
__global__ void k_combine(const float* __restrict__ We, const float* __restrict__ W1,
                          const float* __restrict__ be,
                          float* __restrict__ M, float* __restrict__ v) {
    int f = threadIdx.x;            // 128
    int k = blockIdx.x;             // 0..33; 33 => bias row
    if (k < IN_DIM) {
        float a = 0.0f;
#pragma unroll 8
        for (int j = 0; j < HID; ++j) a += We[k * HID + j] * W1[j * HID + f];
        M[k * HID + f] = a;
    } else {
        float a = 0.0f;
#pragma unroll 8
        for (int j = 0; j < HID; ++j) a += be[j] * W1[j * HID + f];
        v[f] = a;
    }
}

// ---------------- W transpose+cast: Wt[l][c][k] = bf16(W_l[k][c]) ----------------
__global__ void k_wcast3(const float* __restrict__ W1, const float* __restrict__ W2,
                         const float* __restrict__ W3, unsigned short* __restrict__ Wt) {
    int k = blockIdx.x, c = threadIdx.x, l = blockIdx.y;
    const float* W = (l == 0) ? W1 : (l == 1) ? W2 : W3;
    Wt[((size_t)l * HID + c) * HID + k] = f2bf(W[k * HID + c]);
}

// ---------------- t = bf16(x@M + v)  (N x 33 @ 33 x 128) ----------------
__global__ __launch_bounds__(256) void k_gemm_x(const float* __restrict__ x,
                                                const float* __restrict__ M,
                                                const float* __restrict__ v,
                                                unsigned short* __restrict__ tb, int n) {
    __shared__ float sX[32 * IN_DIM];
    int n0 = blockIdx.x * 32;
    int tid = threadIdx.x;
    int cnt = n - n0; if (cnt > 32) cnt = 32;
    for (int idx = tid; idx < cnt * IN_DIM; idx += 256)
        sX[idx] = x[szmul(n0, IN_DIM) + idx];
    __syncthreads();
    int f = tid & 127, g = tid >> 7;
    float Mc[IN_DIM];
#pragma unroll
    for (int k = 0; k < IN_DIM; ++k) Mc[k] = M[k * HID + f];
    float vf = v[f];
    int ndEnd = g * 16 + 16; if (ndEnd > cnt) ndEnd = cnt;
    for (int nd = g * 16; nd < ndEnd; ++nd) {
        float a = vf;
#pragma unroll
        for (int k = 0; k < IN_DIM; ++k) a += sX[nd * IN_DIM + k] * Mc[k];
        tb[szmul(n0 + nd, HID) + f] = f2bf(a);
    }
}

// ---------------- FUSED aggregate + GEMM ----------------
// Phase 1: 16-lane group aggregates one node (4 nodes/wave, looped 4x -> 64 nodes/block);
// relu'd bf16 rows land in a 16KB LDS tile (XOR-swizzled 16B chunks: chunk ^= row&7).
// Phase 2: wave w MFMA-multiplies rows w*16..w*16+15 from LDS by Wt (col-major bf16),
// packed-pair stores to the next layer's message buffer. h never touches global.
__global__ __launch_bounds__(256) void k_agg_gemm(const uint4* __restrict__ tb,
                                                  const int* __restrict__ rowptr,
                                                  const int2* __restrict__ csr,
                                                  const float* __restrict__ selfn,
                                                  const float* __restrict__ bias,
                                                  const unsigned short* __restrict__ Wt,
                                                  unsigned short* __restrict__ Tout, int n) {
    __shared__ unsigned short sh[64][HID];    // 16 KiB
    int tid = threadIdx.x;
    int grp = tid >> 4;                       // 0..15
    int p = tid & 15;                         // uint4 index; features 8p..8p+7
    int nbase = blockIdx.x * 64;
    const float4* bp = reinterpret_cast<const float4*>(bias + p * 8);
    float4 b0 = bp[0], b1 = bp[1];
#pragma unroll
    for (int sub = 0; sub < 4; ++sub) {
        int rrow = sub * 16 + grp;
        int i = nbase + rrow;
        unsigned u0 = 0, u1 = 0, u2 = 0, u3 = 0;
        if (i < n) {
            uint4 sv = tb[szmul(i, 16) + p];
            float sn = selfn[i];
            float a0 = b0.x + sn * bf_lo(sv.x), a1 = b0.y + sn * bf_hi(sv.x);
            float a2 = b0.z + sn * bf_lo(sv.y), a3 = b0.w + sn * bf_hi(sv.y);
            float a4 = b1.x + sn * bf_lo(sv.z), a5 = b1.y + sn * bf_hi(sv.z);
            float a6 = b1.z + sn * bf_lo(sv.w), a7 = b1.w + sn * bf_hi(sv.w);
            int beg = rowptr[i], end = rowptr[i + 1];
#pragma unroll 4
            for (int j = beg; j < end; ++j) {
                int2 e = csr[j];
                float wj = __int_as_float(e.y);
                uint4 r = tb[szmul(e.x, 16) + p];
                a0 += wj * bf_lo(r.x); a1 += wj * bf_hi(r.x);
                a2 += wj * bf_lo(r.y); a3 += wj * bf_hi(r.y);
                a4 += wj * bf_lo(r.z); a5 += wj * bf_hi(r.z);
                a6 += wj * bf_lo(r.w); a7 += wj * bf_hi(r.w);
            }
            u0 = (unsigned)f2bf(fmaxf(a0, 0.f)) | ((unsigned)f2bf(fmaxf(a1, 0.f)) << 16);
            u1 = (unsigned)f2bf(fmaxf(a2, 0.f)) | ((unsigned)f2bf(fmaxf(a3, 0.f)) << 16);
            u2 = (unsigned)f2bf(fmaxf(a4, 0.f)) | ((unsigned)f2bf(fmaxf(a5, 0.f)) << 16);
            u3 = (unsigned)f2bf(fmaxf(a6, 0.f)) | ((unsigned)f2bf(fmaxf(a7, 0.f)) << 16);
        }
        int chunk = p ^ (rrow & 7);
        *reinterpret_cast<uint4*>(&sh[rrow][chunk * 8]) = make_uint4(u0, u1, u2, u3);
    }
    __syncthreads();
    // Phase 2: MFMA GEMM from LDS
    int wave = tid >> 6;
    int lane = tid & 63;
    int r = lane & 15, kg = lane >> 4;
    int rrow = wave * 16 + r;
    short8 af[4];
#pragma unroll
    for (int kk = 0; kk < 4; ++kk) {
        int chunk = (kk * 4 + kg) ^ (rrow & 7);
        af[kk] = *reinterpret_cast<const short8*>(&sh[rrow][chunk * 8]);
    }
    floatx4 acc[8];
#pragma unroll
    for (int ct = 0; ct < 8; ++ct) acc[ct] = floatx4{0.f, 0.f, 0.f, 0.f};
#pragma unroll
    for (int kk = 0; kk < 4; ++kk) {
#pragma unroll
        for (int ct = 0; ct < 8; ++ct) {
            short8 bf = *reinterpret_cast<const short8*>(
                Wt + (size_t)(ct * 16 + r) * HID + kk * 32 + kg * 8);
            acc[ct] = __builtin_amdgcn_mfma_f32_16x16x32_bf16(af[kk], bf, acc[ct], 0, 0, 0);
        }
    }
    bool even = (r & 1) == 0;
    int row0 = nbase + wave * 16;
#pragma unroll
    for (int ct = 0; ct < 8; ++ct) {
#pragma unroll
        for (int reg = 0; reg < 4; ++reg) {
            float o = __shfl_xor(acc[ct][reg], 1);
            int orow = row0 + kg * 4 + reg;
            if (even && orow < n) {
                unsigned pk = (unsigned)f2bf(acc[ct][reg]) | ((unsigned)f2bf(o) << 16);
                *reinterpret_cast<unsigned*>(Tout + szmul(orow, HID) + ct * 16 + r) = pk;
            }
        }
    }
}

// ---------------- final aggregate (no GEMM after) ----------------
__global__ __launch_bounds__(256) void k_aggregate(const uint4* __restrict__ tb,
                                                   const int* __restrict__ rowptr,
                                                   const int2* __restrict__ csr,
                                                   const float* __restrict__ selfn,
                                                   const float* __restrict__ bias,
                                                   uint4* __restrict__ hout, int n) {
    int i = (blockIdx.x * 256 + threadIdx.x) >> 4;   // node per 16-lane group
    if (i >= n) return;
    int p = threadIdx.x & 15;
    uint4 sv = tb[szmul(i, 16) + p];
    float sn = selfn[i];
    const float4* bp = reinterpret_cast<const float4*>(bias + p * 8);
    float4 b0 = bp[0], b1 = bp[1];
    float a0 = b0.x + sn * bf_lo(sv.x), a1 = b0.y + sn * bf_hi(sv.x);
    float a2 = b0.z + sn * bf_lo(sv.y), a3 = b0.w + sn * bf_hi(sv.y);
    float a4 = b1.x + sn * bf_lo(sv.z), a5 = b1.y + sn * bf_hi(sv.z);
    float a6 = b1.z + sn * bf_lo(sv.w), a7 = b1.w + sn * bf_hi(sv.w);
    int beg = rowptr[i], end = rowptr[i + 1];
#pragma unroll 4
    for (int j = beg; j < end; ++j) {
        int2 e = csr[j];
        float wj = __int_as_float(e.y);
        uint4 r = tb[szmul(e.x, 16) + p];
        a0 += wj * bf_lo(r.x); a1 += wj * bf_hi(r.x);
        a2 += wj * bf_lo(r.y); a3 += wj * bf_hi(r.y);
        a4 += wj * bf_lo(r.z); a5 += wj * bf_hi(r.z);
        a6 += wj * bf_lo(r.w); a7 += wj * bf_hi(r.w);
    }
    unsigned u0 = (unsigned)f2bf(fmaxf(a0, 0.f)) | ((unsigned)f2bf(fmaxf(a1, 0.f)) << 16);
    unsigned u1 = (unsigned)f2bf(fmaxf(a2, 0.f)) | ((unsigned)f2bf(fmaxf(a3, 0.f)) << 16);
    unsigned u2 = (unsigned)f2bf(fmaxf(a4, 0.f)) | ((unsigned)f2bf(fmaxf(a5, 0.f)) << 16);
    unsigned u3 = (unsigned)f2bf(fmaxf(a6, 0.f)) | ((unsigned)f2bf(fmaxf(a7, 0.f)) << 16);
    hout[szmul(i, 16) + p] = make_uint4(u0, u1, u2, u3);
}

// ---------------- pooling ----------------
__global__ void k_gcount_bs(const int* __restrict__ batch, int* gcnt, int n) {
    int g = threadIdx.x;
    if (g >= NG) return;
    int lo = 0, hi = n;
    while (lo < hi) { int mid = (lo + hi) >> 1; if (batch[mid] < g) lo = mid + 1; else hi = mid; }
    int start = lo;
    lo = 0; hi = n;
    while (lo < hi) { int mid = (lo + hi) >> 1; if (batch[mid] < g + 1) lo = mid + 1; else hi = mid; }
    gcnt[g] = lo - start;
}

__global__ __launch_bounds__(128) void k_pool(const unsigned short* __restrict__ h,
                                              const int* __restrict__ batch,
                                              float* gsum, int n) {
    int f = threadIdx.x;
    int i0 = blockIdx.x * 32;
    int i1 = min(i0 + 32, n);
    if (i0 >= n) return;
    float acc = 0.0f;
    int cur = batch[i0];
    for (int i = i0; i < i1; ++i) {
        int g = batch[i];
        if (g != cur) { atomicAdd(&gsum[cur * HID + f], acc); acc = 0.0f; cur = g; }
        acc += __uint_as_float((unsigned)h[szmul(i, HID) + f] << 16);
    }
    atomicAdd(&gsum[cur * HID + f], acc);
}

// ---------------- readout MLP ----------------
__global__ __launch_bounds__(128) void k_mlp(const float* __restrict__ gsum,
                                             const int* __restrict__ gcnt,
                                             const float* __restrict__ Wr1, const float* __restrict__ br1,
                                             const float* __restrict__ Wr2, const float* __restrict__ br2,
                                             const float* __restrict__ Wr3,
                                             float* __restrict__ out) {
    int g = blockIdx.x;
    int t = threadIdx.x;
    __shared__ float p[HID];
    __shared__ float r1[64];
    __shared__ float r2[32];
    float c = fmaxf((float)gcnt[g], 1.0f);
    p[t] = gsum[g * HID + t] / c;
    __syncthreads();
    if (t < 64) {
        float a = br1[t];
#pragma unroll 8
        for (int k = 0; k < HID; ++k) a += p[k] * Wr1[k * 64 + t];
        r1[t] = fmaxf(a, 0.0f);
    }
    __syncthreads();
    if (t < 32) {
        float a = br2[t];
#pragma unroll 8
        for (int k = 0; k < 64; ++k) a += r1[k] * Wr2[k * 32 + t];
        r2[t] = fmaxf(a, 0.0f);
    }
    __syncthreads();
    if (t < NCLS) {
        float a = 0.0f;
#pragma unroll
        for (int k = 0; k < 32; ++k) a += r2[k] * Wr3[k * NCLS + t];
        out[g * NCLS + t] = a;
    }
}

extern "C" void kernel_launch(void* const* d_in, const int* in_sizes, int n_in,
                              void* d_out, int out_size, void* d_ws, size_t ws_size,
                              hipStream_t stream) {
    const float* x     = (const float*)d_in[0];
    const int*   ei    = (const int*)d_in[1];
    const float* ew    = (const float*)d_in[2];
    const int*   batch = (const int*)d_in[3];
    const float* We  = (const float*)d_in[4];
    const float* be  = (const float*)d_in[5];
    const float* Wl[4] = { (const float*)d_in[6], (const float*)d_in[8],
                           (const float*)d_in[10], (const float*)d_in[12] };
    const float* bl[4] = { (const float*)d_in[7], (const float*)d_in[9],
                           (const float*)d_in[11], (const float*)d_in[13] };
    const float* Wr1 = (const float*)d_in[14];
    const float* br1 = (const float*)d_in[15];
    const float* Wr2 = (const float*)d_in[16];
    const float* br2 = (const float*)d_in[17];
    const float* Wr3 = (const float*)d_in[18];
    float* out = (float*)d_out;

    const int N = in_sizes[3];      // 100000
    const int E = in_sizes[2];      // 1600000
    const int* row = ei;
    const int* col = ei + E;
    const int nbk = (N + 255) >> 8; // 391 buckets

    // workspace layout
    char* w = (char*)d_ws;
    size_t off = 0;
    auto alloc = [&](size_t bytes) -> void* {
        void* p = w + off;
        off = (off + bytes + 255) & ~(size_t)255;
        return p;
    };
    float* dinv       = (float*)alloc((size_t)N * 4);   // wsum, then dinv in place
    float* selfn      = (float*)alloc((size_t)N * 4);
    int*   rowptr     = (int*)  alloc((size_t)(N + 1) * 4);
    int*   bucket_cnt = (int*)  alloc(513 * 4);   // becomes bucket_base after scan
    int*   bucket_fill= (int*)  alloc(513 * 4);
    int2*  csr        = (int2*) alloc((size_t)E * 8);
    unsigned short* bufA = (unsigned short*)alloc((size_t)N * HID * 2);  // msg ping
    unsigned short* bufB = (unsigned short*)alloc((size_t)N * HID * 2);  // msg pong
    unsigned short* hfin = (unsigned short*)alloc((size_t)N * HID * 2);  // final h
    unsigned short* Wt = (unsigned short*)alloc((size_t)3 * HID * HID * 2); // bf16 W^T x3
    float* M          = (float*)alloc((size_t)IN_DIM * HID * 4);
    float* vbe        = (float*)alloc((size_t)HID * 4);
    float* gsum       = (float*)alloc((size_t)NG * HID * 4);
    int*   gcnt       = (int*)  alloc((size_t)NG * 4);
    uint2* binned     = (uint2*)bufA;  // alias: consumed before bufA first written
    (void)ws_size;

    auto cdiv = [](int a, int b) { return (a + b - 1) / b; };

    // ---- binned CSR build (deg/norm + rowptr folded in) ----
    k_init<<<64, 256, 0, stream>>>(bucket_cnt, bucket_fill, gsum);
    k_bhist<<<256, 256, 0, stream>>>(col, bucket_cnt, E, nbk);
    k_scan_small<<<1, 512, 0, stream>>>(bucket_cnt, nbk);        // -> bucket_base
    k_bin_scatter<<<cdiv(E, 4096), 256, 0, stream>>>(row, col, ew, bucket_cnt,
                                                     bucket_fill, binned, E, nbk);
    k_bucket_rowptr<<<nbk, 256, 0, stream>>>(binned, bucket_cnt, rowptr, dinv, N);
    k_dinv<<<cdiv(N + 1, 256), 256, 0, stream>>>(dinv, selfn, rowptr, N, E);
    k_bucket_scatter<<<nbk, 256, 0, stream>>>(binned, bucket_cnt, rowptr, dinv, csr, N);

    // fused layer-1 weights + bf16 transposed W for layers 2-4
    k_combine<<<IN_DIM + 1, HID, 0, stream>>>(We, Wl[0], be, M, vbe);
    k_wcast3<<<dim3(HID, 3), HID, 0, stream>>>(Wl[1], Wl[2], Wl[3], Wt);

    // chain: tb1 = bf16(x@(We@W1) + be@W1)   [bufB — binned lives in bufA]
    k_gemm_x<<<cdiv(N, 32), 256, 0, stream>>>(x, M, vbe, bufB, N);
    // fused: agg(bl[0]) + GEMM W2 -> bufA ; agg(bl[1]) + W3 -> bufB ; agg(bl[2]) + W4 -> bufA
    k_agg_gemm<<<cdiv(N, 64), 256, 0, stream>>>((const uint4*)bufB, rowptr, csr, selfn,
                                                bl[0], Wt + 0 * (size_t)HID * HID, bufA, N);
    k_agg_gemm<<<cdiv(N, 64), 256, 0, stream>>>((const uint4*)bufA, rowptr, csr, selfn,
                                                bl[1], Wt + 1 * (size_t)HID * HID, bufB, N);
    k_agg_gemm<<<cdiv(N, 64), 256, 0, stream>>>((const uint4*)bufB, rowptr, csr, selfn,
                                                bl[2], Wt + 2 * (size_t)HID * HID, bufA, N);
    // final aggregate -> hfin
    k_aggregate<<<cdiv(N, 16), 256, 0, stream>>>((const uint4*)bufA, rowptr, csr,
                                                 selfn, bl[3], (uint4*)hfin, N);

    k_gcount_bs<<<1, 128, 0, stream>>>(batch, gcnt, N);
    k_pool<<<cdiv(N, 32), 128, 0, stream>>>(hfin, batch, gsum, N);
    k_mlp<<<NG, HID, 0, stream>>>(gsum, gcnt, Wr1, br1, Wr2, br2, Wr3, out);

    (void)out_size; (void)n_in;
}

// Round 17
// 462.941 us; speedup vs baseline: 1.0486x; 1.0486x over previous
//
#include <hip/hip_runtime.h>
#include <hip/hip_bf16.h>

#define NN 100000
#define NE 1600000
#define IN_DIM 33
#define HID 128
#define NG 128
#define NCLS 10

using short8 = __attribute__((ext_vector_type(8))) short;
using floatx4 = __attribute__((ext_vector_type(4))) float;

static __device__ __forceinline__ size_t szmul(int a, int b) {
    return (size_t)a * (size_t)b;
}

// bf16 helpers: pack with RNE, unpack via bit ops (cheap: 1 VALU each)
static __device__ __forceinline__ unsigned short f2bf(float f) {
    unsigned u = __float_as_uint(f);
    u += 0x7fffu + ((u >> 16) & 1u);
    return (unsigned short)(u >> 16);
}
static __device__ __forceinline__ float bf_lo(unsigned u) { return __uint_as_float(u << 16); }
static __device__ __forceinline__ float bf_hi(unsigned u) { return __uint_as_float(u & 0xffff0000u); }

// ---------------- init ----------------
__global__ void k_init(int* bucket_cnt, int* bucket_fill, float* gsum) {
    int i = blockIdx.x * blockDim.x + threadIdx.x;
    if (i < 513) { bucket_cnt[i] = 0; bucket_fill[i] = 0; }
    if (i < NG * HID) gsum[i] = 0.0f;
}

// ---------------- binned CSR build ----------------
// bucket = col >> 8 (256 nodes per bucket, nbk = ceil(N/256) = 391)

__global__ __launch_bounds__(256) void k_bhist(const int* __restrict__ col,
                                               int* __restrict__ bucket_cnt, int e, int nbk) {
    __shared__ int hist[512];
    int tid = threadIdx.x;
    for (int i = tid; i < nbk; i += 256) hist[i] = 0;
    __syncthreads();
    for (int i = blockIdx.x * 256 + tid; i < e; i += 256 * 256)
        atomicAdd(&hist[col[i] >> 8], 1);
    __syncthreads();
    for (int i = tid; i < nbk; i += 256)
        if (hist[i]) atomicAdd(&bucket_cnt[i], hist[i]);
}

// parallel exclusive scan over nb <= 512 elements, in place; data[nb] = total
__global__ void k_scan_small(int* data, int nb) {
    __shared__ int s[512];
    int t = threadIdx.x;
    int v = (t < nb) ? data[t] : 0;
    s[t] = v;
    __syncthreads();
    for (int o = 1; o < 512; o <<= 1) {
        int a = (t >= o) ? s[t - o] : 0;
        __syncthreads();
        s[t] += a;
        __syncthreads();
    }
    if (t < nb) data[t] = s[t] - v;
    if (t == nb - 1) data[nb] = s[t];
}

// Pass C: binned scatter. 4096 edges/block, vectorized int4/float4 input reads;
// multisplit by bucket in LDS, grouped writes per bucket.
// Record: x = (col&255)<<17 | src (src < 2^17), y = raw w bits.
__global__ __launch_bounds__(256) void k_bin_scatter(const int* __restrict__ row,
                                                     const int* __restrict__ col,
                                                     const float* __restrict__ w,
                                                     const int* __restrict__ bucket_base,
                                                     int* __restrict__ bucket_fill,
                                                     uint2* __restrict__ binned, int e, int nbk) {
    __shared__ int hist[512], rnk[512], basub[512];
    int tid = threadIdx.x;
    int c0 = blockIdx.x * 4096;
    for (int i = tid; i < nbk; i += 256) { hist[i] = 0; rnk[i] = 0; }
    __syncthreads();
    int base = c0 + tid * 16;
    int myb[16]; unsigned myp[16]; unsigned myw[16];
    if (base + 16 <= e) {
#pragma unroll
        for (int q = 0; q < 4; ++q) {
            int4 c4 = reinterpret_cast<const int4*>(col + base)[q];
            int4 r4 = reinterpret_cast<const int4*>(row + base)[q];
            float4 w4 = reinterpret_cast<const float4*>(w + base)[q];
            int cs[4] = {c4.x, c4.y, c4.z, c4.w};
            int rs[4] = {r4.x, r4.y, r4.z, r4.w};
            float ws[4] = {w4.x, w4.y, w4.z, w4.w};
#pragma unroll
            for (int v = 0; v < 4; ++v) {
                int c = cs[v];
                int b = c >> 8;
                myb[q * 4 + v] = b;
                myp[q * 4 + v] = ((unsigned)(c & 255) << 17) | (unsigned)rs[v];
                myw[q * 4 + v] = __float_as_uint(ws[v]);
                atomicAdd(&hist[b], 1);
            }
        }
    } else {
#pragma unroll
        for (int v = 0; v < 16; ++v) {
            int idx = base + v;
            int b = -1;
            if (idx < e) {
                int c = col[idx];
                myw[v] = __float_as_uint(w[idx]);
                b = c >> 8;
                myp[v] = ((unsigned)(c & 255) << 17) | (unsigned)row[idx];
                atomicAdd(&hist[b], 1);
            }
            myb[v] = b;
        }
    }
    __syncthreads();
    for (int i = tid; i < nbk; i += 256) {
        int c = hist[i];
        basub[i] = (c > 0) ? (bucket_base[i] + atomicAdd(&bucket_fill[i], c)) : 0;
    }
    __syncthreads();
#pragma unroll
    for (int u = 0; u < 16; ++u) {
        int b = myb[u];
        if (b >= 0) {
            int rk = atomicAdd(&rnk[b], 1);
            binned[basub[b] + rk] = make_uint2(myp[u], myw[u]);
        }
    }
}

// Pass D1: per-bucket node histogram + weight sums; in-LDS scan -> rowptr;
// dinv/selfn computed inline (dinv[i] depends only on this bucket's wsum).
__global__ __launch_bounds__(256) void k_bucket_rowptr(const uint2* __restrict__ binned,
                                                       const int* __restrict__ bucket_base,
                                                       int* __restrict__ rowptr,
                                                       float* __restrict__ dinv,
                                                       float* __restrict__ selfn,
                                                       int n, int etot) {
    __shared__ int c256[256];
    __shared__ float s256[256];
    __shared__ int sc[256];
    int b = blockIdx.x, tid = threadIdx.x;
    c256[tid] = 0;
    s256[tid] = 0.0f;
    __syncthreads();
    int beg = bucket_base[b], end = bucket_base[b + 1];
    for (int e2 = beg + tid; e2 < end; e2 += 256) {
        uint2 rec = binned[e2];
        int lo = (rec.x >> 17) & 255;
        atomicAdd(&c256[lo], 1);
        atomicAdd(&s256[lo], __uint_as_float(rec.y));
    }
    __syncthreads();
    int v = c256[tid];
    sc[tid] = v;
    __syncthreads();
    for (int o = 1; o < 256; o <<= 1) {
        int a = (tid >= o) ? sc[tid - o] : 0;
        __syncthreads();
        sc[tid] += a;
        __syncthreads();
    }
    if (b == 0 && tid == 0) rowptr[n] = etot;
    int node = b * 256 + tid;
    if (node < n) {
        rowptr[node] = beg + sc[tid] - v;   // exclusive prefix within bucket
        float d = 1.0f + s256[tid];
        float di = (d > 0.0f) ? (1.0f / sqrtf(d)) : 0.0f;
        dinv[node] = di;
        selfn[node] = di * di;
    }
}

// Pass D2: per-bucket final scatter with normalization folded in
__global__ __launch_bounds__(256) void k_bucket_scatter(const uint2* __restrict__ binned,
                                                        const int* __restrict__ bucket_base,
                                                        const int* __restrict__ rowptr,
                                                        const float* __restrict__ dinv,
                                                        int2* __restrict__ csr, int n) {
    __shared__ int f256[256];
    int b = blockIdx.x, tid = threadIdx.x;
    f256[tid] = 0;
    __syncthreads();
    int beg = bucket_base[b], end = bucket_base[b + 1];
    for (int e2 = beg + tid; e2 < end; e2 += 256) {
        uint2 rec = binned[e2];
        int lo = (rec.x >> 17) & 255;
        int node = (b << 8) | lo;
        int src = rec.x & 0x1FFFF;
        float nw = dinv[src] * __uint_as_float(rec.y) * dinv[node];
        int pos = rowptr[node] + atomicAdd(&f256[lo], 1);
        csr[pos] = make_int2(src, __float_as_int(nw));
    }
    (void)n;
}

// ---------------- merged weight prep ----------------
// blocks [0,33]: M = We@W1 rows / v = be@W1.  blocks [34,417]: Wt[l][c][k] = bf16(W[k][c])
__global__ __launch_bounds__(128) void k_prep_w(const float* __restrict__ We,
                                                const float* __restrict__ be,
                                                const float* __restrict__ W1,
                                                const float* __restrict__ W2,
                                                const float* __restrict__ W3,
                                                const float* __restrict__ W4,
                                                float* __restrict__ M, float* __restrict__ v,
                                                unsigned short* __restrict__ Wt) {
    int bid = blockIdx.x;
    int t = threadIdx.x;
    if (bid <= IN_DIM) {
        if (bid < IN_DIM) {
            float a = 0.0f;
#pragma unroll 8
            for (int j = 0; j < HID; ++j) a += We[bid * HID + j] * W1[j * HID + t];
            M[bid * HID + t] = a;
        } else {
            float a = 0.0f;
#pragma unroll 8
            for (int j = 0; j < HID; ++j) a += be[j] * W1[j * HID + t];
            v[t] = a;
        }
    } else {
        int idx = bid - (IN_DIM + 1);
        int l = idx >> 7, k = idx & 127;
        const float* W = (l == 0) ? W2 : (l == 1) ? W3 : W4;
        Wt[((size_t)l * HID + t) * HID + k] = f2bf(W[k * HID + t]);
    }
}

// ---------------- t = bf16(x@M + v)  (N x 33 @ 33 x 128) ----------------
__global__ __launch_bounds__(256) void k_gemm_x(const float* __restrict__ x,
                                                const float* __restrict__ M,
                                                const float* __restrict__ v,
                                                unsigned short* __restrict__ tb, int n) {
    __shared__ float sX[32 * IN_DIM];
    int n0 = blockIdx.x * 32;
    int tid = threadIdx.x;
    int cnt = n - n0; if (cnt > 32) cnt = 32;
    for (int idx = tid; idx < cnt * IN_DIM; idx += 256)
        sX[idx] = x[szmul(n0, IN_DIM) + idx];
    __syncthreads();
    int f = tid & 127, g = tid >> 7;
    float Mc[IN_DIM];
#pragma unroll
    for (int k = 0; k < IN_DIM; ++k) Mc[k] = M[k * HID + f];
    float vf = v[f];
    int ndEnd = g * 16 + 16; if (ndEnd > cnt) ndEnd = cnt;
    for (int nd = g * 16; nd < ndEnd; ++nd) {
        float a = vf;
#pragma unroll
        for (int k = 0; k < IN_DIM; ++k) a += sX[nd * IN_DIM + k] * Mc[k];
        tb[szmul(n0 + nd, HID) + f] = f2bf(a);
    }
}

// ---------------- MFMA GEMM: T = A @ W  (A: n x 128 bf16, Wt: 128x128 bf16 col-major) ----
// 4 waves/block, wave = 32 rows x 128 cols; each B-fragment load feeds 2 MFMAs.
// 16 independent accumulator chains. Stores packed to 4B via lane-pair shfl.
__global__ __launch_bounds__(256) void k_gemm_mfma(const unsigned short* __restrict__ A,
                                                   const unsigned short* __restrict__ Wt,
                                                   unsigned short* __restrict__ T, int n) {
    int wave = threadIdx.x >> 6;
    int lane = threadIdx.x & 63;
    int r = lane & 15, kg = lane >> 4;
    int row0 = blockIdx.x * 128 + wave * 32;
    short8 af0[4], af1[4];
#pragma unroll
    for (int kk = 0; kk < 4; ++kk) {
        int a0 = row0 + r, a1 = row0 + 16 + r;
        af0[kk] = (a0 < n) ? *reinterpret_cast<const short8*>(A + szmul(a0, HID) + kk * 32 + kg * 8)
                           : short8{0, 0, 0, 0, 0, 0, 0, 0};
        af1[kk] = (a1 < n) ? *reinterpret_cast<const short8*>(A + szmul(a1, HID) + kk * 32 + kg * 8)
                           : short8{0, 0, 0, 0, 0, 0, 0, 0};
    }
    floatx4 acc0[8], acc1[8];
#pragma unroll
    for (int ct = 0; ct < 8; ++ct) {
        acc0[ct] = floatx4{0.f, 0.f, 0.f, 0.f};
        acc1[ct] = floatx4{0.f, 0.f, 0.f, 0.f};
    }
#pragma unroll
    for (int kk = 0; kk < 4; ++kk) {
#pragma unroll
        for (int ct = 0; ct < 8; ++ct) {
            short8 bf = *reinterpret_cast<const short8*>(
                Wt + (size_t)(ct * 16 + r) * HID + kk * 32 + kg * 8);
            acc0[ct] = __builtin_amdgcn_mfma_f32_16x16x32_bf16(af0[kk], bf, acc0[ct], 0, 0, 0);
            acc1[ct] = __builtin_amdgcn_mfma_f32_16x16x32_bf16(af1[kk], bf, acc1[ct], 0, 0, 0);
        }
    }
    bool even = (r & 1) == 0;
#pragma unroll
    for (int ct = 0; ct < 8; ++ct) {
#pragma unroll
        for (int reg = 0; reg < 4; ++reg) {
            float o0 = __shfl_xor(acc0[ct][reg], 1);
            float o1 = __shfl_xor(acc1[ct][reg], 1);
            int orow0 = row0 + kg * 4 + reg;
            int orow1 = orow0 + 16;
            if (even && orow0 < n) {
                unsigned pk = (unsigned)f2bf(acc0[ct][reg]) | ((unsigned)f2bf(o0) << 16);
                *reinterpret_cast<unsigned*>(T + szmul(orow0, HID) + ct * 16 + r) = pk;
            }
            if (even && orow1 < n) {
                unsigned pk = (unsigned)f2bf(acc1[ct][reg]) | ((unsigned)f2bf(o1) << 16);
                *reinterpret_cast<unsigned*>(T + szmul(orow1, HID) + ct * 16 + r) = pk;
            }
        }
    }
}

// ---------------- aggregate: h[i] = relu(b + selfn[i]*t[i] + sum_e w_e * t[src_e]) ----
// Group-per-node: 16-lane group owns one node (4 nodes/wave). Edge records read
// directly from csr (group-uniform 8B, L1-hit); lane p holds features 8p..8p+7.
__global__ __launch_bounds__(256) void k_aggregate(const uint4* __restrict__ tb,
                                                   const int* __restrict__ rowptr,
                                                   const int2* __restrict__ csr,
                                                   const float* __restrict__ selfn,
                                                   const float* __restrict__ bias,
                                                   uint4* __restrict__ hout, int n) {
    int i = (blockIdx.x * 256 + threadIdx.x) >> 4;   // node per 16-lane group
    if (i >= n) return;
    int p = threadIdx.x & 15;                 // uint4 index in row; features 8p..8p+7
    uint4 sv = tb[szmul(i, 16) + p];
    float sn = selfn[i];
    const float4* bp = reinterpret_cast<const float4*>(bias + p * 8);
    float4 b0 = bp[0], b1 = bp[1];
    float a0 = b0.x + sn * bf_lo(sv.x), a1 = b0.y + sn * bf_hi(sv.x);
    float a2 = b0.z + sn * bf_lo(sv.y), a3 = b0.w + sn * bf_hi(sv.y);
    float a4 = b1.x + sn * bf_lo(sv.z), a5 = b1.y + sn * bf_hi(sv.z);
    float a6 = b1.z + sn * bf_lo(sv.w), a7 = b1.w + sn * bf_hi(sv.w);
    int beg = rowptr[i], end = rowptr[i + 1];
#pragma unroll 4
    for (int j = beg; j < end; ++j) {
        int2 e = csr[j];                      // uniform within group -> broadcast
        float wj = __int_as_float(e.y);
        uint4 r = tb[szmul(e.x, 16) + p];
        a0 += wj * bf_lo(r.x); a1 += wj * bf_hi(r.x);
        a2 += wj * bf_lo(r.y); a3 += wj * bf_hi(r.y);
        a4 += wj * bf_lo(r.z); a5 += wj * bf_hi(r.z);
        a6 += wj * bf_lo(r.w); a7 += wj * bf_hi(r.w);
    }
    unsigned u0 = (unsigned)f2bf(fmaxf(a0, 0.f)) | ((unsigned)f2bf(fmaxf(a1, 0.f)) << 16);
    unsigned u1 = (unsigned)f2bf(fmaxf(a2, 0.f)) | ((unsigned)f2bf(fmaxf(a3, 0.f)) << 16);
    unsigned u2 = (unsigned)f2bf(fmaxf(a4, 0.f)) | ((unsigned)f2bf(fmaxf(a5, 0.f)) << 16);
    unsigned u3 = (unsigned)f2bf(fmaxf(a6, 0.f)) | ((unsigned)f2bf(fmaxf(a7, 0.f)) << 16);
    hout[szmul(i, 16) + p] = make_uint4(u0, u1, u2, u3);
}

// ---------------- pooling ----------------
__global__ __launch_bounds__(128) void k_pool(const unsigned short* __restrict__ h,
                                              const int* __restrict__ batch,
                                              float* gsum, int n) {
    int f = threadIdx.x;
    int i0 = blockIdx.x * 32;
    int i1 = min(i0 + 32, n);
    if (i0 >= n) return;
    float acc = 0.0f;
    int cur = batch[i0];
    for (int i = i0; i < i1; ++i) {
        int g = batch[i];
        if (g != cur) { atomicAdd(&gsum[cur * HID + f], acc); acc = 0.0f; cur = g; }
        acc += __uint_as_float((unsigned)h[szmul(i, HID) + f] << 16);
    }
    atomicAdd(&gsum[cur * HID + f], acc);
}

// ---------------- readout MLP (graph count inlined via binary search) ----------------
__global__ __launch_bounds__(128) void k_mlp(const float* __restrict__ gsum,
                                             const int* __restrict__ batch, int n,
                                             const float* __restrict__ Wr1, const float* __restrict__ br1,
                                             const float* __restrict__ Wr2, const float* __restrict__ br2,
                                             const float* __restrict__ Wr3,
                                             float* __restrict__ out) {
    int g = blockIdx.x;
    int t = threadIdx.x;
    __shared__ float p[HID];
    __shared__ float r1[64];
    __shared__ float r2[32];
    // count nodes in graph g (uniform across block; cheap)
    int lo = 0, hi = n;
    while (lo < hi) { int mid = (lo + hi) >> 1; if (batch[mid] < g) lo = mid + 1; else hi = mid; }
    int start = lo;
    lo = 0; hi = n;
    while (lo < hi) { int mid = (lo + hi) >> 1; if (batch[mid] < g + 1) lo = mid + 1; else hi = mid; }
    float c = fmaxf((float)(lo - start), 1.0f);
    p[t] = gsum[g * HID + t] / c;
    __syncthreads();
    if (t < 64) {
        float a = br1[t];
#pragma unroll 8
        for (int k = 0; k < HID; ++k) a += p[k] * Wr1[k * 64 + t];
        r1[t] = fmaxf(a, 0.0f);
    }
    __syncthreads();
    if (t < 32) {
        float a = br2[t];
#pragma unroll 8
        for (int k = 0; k < 64; ++k) a += r1[k] * Wr2[k * 32 + t];
        r2[t] = fmaxf(a, 0.0f);
    }
    __syncthreads();
    if (t < NCLS) {
        float a = 0.0f;
#pragma unroll
        for (int k = 0; k < 32; ++k) a += r2[k] * Wr3[k * NCLS + t];
        out[g * NCLS + t] = a;
    }
}

extern "C" void kernel_launch(void* const* d_in, const int* in_sizes, int n_in,
                              void* d_out, int out_size, void* d_ws, size_t ws_size,
                              hipStream_t stream) {
    const float* x     = (const float*)d_in[0];
    const int*   ei    = (const int*)d_in[1];
    const float* ew    = (const float*)d_in[2];
    const int*   batch = (const int*)d_in[3];
    const float* We  = (const float*)d_in[4];
    const float* be  = (const float*)d_in[5];
    const float* Wl[4] = { (const float*)d_in[6], (const float*)d_in[8],
                           (const float*)d_in[10], (const float*)d_in[12] };
    const float* bl[4] = { (const float*)d_in[7], (const float*)d_in[9],
                           (const float*)d_in[11], (const float*)d_in[13] };
    const float* Wr1 = (const float*)d_in[14];
    const float* br1 = (const float*)d_in[15];
    const float* Wr2 = (const float*)d_in[16];
    const float* br2 = (const float*)d_in[17];
    const float* Wr3 = (const float*)d_in[18];
    float* out = (float*)d_out;

    const int N = in_sizes[3];      // 100000
    const int E = in_sizes[2];      // 1600000
    const int* row = ei;
    const int* col = ei + E;
    const int nbk = (N + 255) >> 8; // 391 buckets

    // workspace layout
    char* w = (char*)d_ws;
    size_t off = 0;
    auto alloc = [&](size_t bytes) -> void* {
        void* p = w + off;
        off = (off + bytes + 255) & ~(size_t)255;
        return p;
    };
    float* dinv       = (float*)alloc((size_t)N * 4);
    float* selfn      = (float*)alloc((size_t)N * 4);
    int*   rowptr     = (int*)  alloc((size_t)(N + 1) * 4);
    int*   bucket_cnt = (int*)  alloc(513 * 4);   // becomes bucket_base after scan
    int*   bucket_fill= (int*)  alloc(513 * 4);
    int2*  csr        = (int2*) alloc((size_t)E * 8);
    unsigned short* h  = (unsigned short*)alloc((size_t)N * HID * 2);  // bf16 activations
    unsigned short* tb = (unsigned short*)alloc((size_t)N * HID * 2);  // bf16 messages
    unsigned short* Wt = (unsigned short*)alloc((size_t)3 * HID * HID * 2); // bf16 W^T x3
    float* M          = (float*)alloc((size_t)IN_DIM * HID * 4);
    float* vbe        = (float*)alloc((size_t)HID * 4);
    float* gsum       = (float*)alloc((size_t)NG * HID * 4);
    uint2* binned     = (uint2*)tb;  // alias: consumed before tb first written
    (void)ws_size;

    auto cdiv = [](int a, int b) { return (a + b - 1) / b; };

    // ---- binned CSR build (deg/norm + rowptr + dinv folded in) ----
    k_init<<<64, 256, 0, stream>>>(bucket_cnt, bucket_fill, gsum);
    k_bhist<<<256, 256, 0, stream>>>(col, bucket_cnt, E, nbk);
    k_scan_small<<<1, 512, 0, stream>>>(bucket_cnt, nbk);        // -> bucket_base
    k_bin_scatter<<<cdiv(E, 4096), 256, 0, stream>>>(row, col, ew, bucket_cnt,
                                                     bucket_fill, binned, E, nbk);
    k_bucket_rowptr<<<nbk, 256, 0, stream>>>(binned, bucket_cnt, rowptr, dinv, selfn, N, E);
    k_bucket_scatter<<<nbk, 256, 0, stream>>>(binned, bucket_cnt, rowptr, dinv, csr, N);

    // merged weight prep: M/vbe + bf16 W^T x3
    k_prep_w<<<IN_DIM + 1 + 3 * HID, HID, 0, stream>>>(We, be, Wl[0], Wl[1], Wl[2], Wl[3],
                                                       M, vbe, Wt);

    // layer 1: t = bf16(x@(We@W1) + be@W1); h = relu(agg(t) + b1)
    k_gemm_x<<<cdiv(N, 32), 256, 0, stream>>>(x, M, vbe, tb, N);
    k_aggregate<<<cdiv(N, 16), 256, 0, stream>>>((const uint4*)tb, rowptr, csr,
                                                 selfn, bl[0], (uint4*)h, N);

    // layers 2-4: MFMA bf16 GEMM + bf16 aggregate
    for (int l = 1; l < 4; ++l) {
        k_gemm_mfma<<<cdiv(N, 128), 256, 0, stream>>>(h, Wt + (size_t)(l - 1) * HID * HID,
                                                      tb, N);
        k_aggregate<<<cdiv(N, 16), 256, 0, stream>>>((const uint4*)tb, rowptr, csr,
                                                     selfn, bl[l], (uint4*)h, N);
    }

    k_pool<<<cdiv(N, 32), 128, 0, stream>>>(h, batch, gsum, N);
    k_mlp<<<NG, HID, 0, stream>>>(gsum, batch, N, Wr1, br1, Wr2, br2, Wr3, out);

    (void)out_size; (void)n_in;
}